// Round 3
// baseline (226.490 us; speedup 1.0000x reference)
//
#include <hip/hip_runtime.h>

// Sparsemax over rows: B=131072, D=256, fp32.
// 2 rows per 64-lane wave, interleaved: two independent Michelot chains
// overlap their shuffle-butterfly latency. Each lane holds one float4 per row.
// tau* ∈ [max-1, max) => start from A0={z>max-1} (tight superset).
// Division replaced by v_rcp_f32 (c is a small integer; 1-ulp rcp shifts tau
// by ~1e-7 -- far under the 2e-2 threshold; termination is set-stability).

#define D_COLS 256

#if defined(__has_builtin) && __has_builtin(__builtin_amdgcn_rcpf)
#define FAST_RCP(x) __builtin_amdgcn_rcpf(x)
#else
#define FAST_RCP(x) (1.0f / (x))
#endif

__global__ __launch_bounds__(256) void sparsemax_kernel(
    const float* __restrict__ x, float* __restrict__ out, int nrows) {
  const int wave = threadIdx.x >> 6;
  const int lane = threadIdx.x & 63;
  const int row0 = (blockIdx.x * 4 + wave) * 2;  // this wave's row pair
  if (row0 >= nrows) return;

  const float4 v0 = ((const float4*)(x + (size_t)row0 * D_COLS))[lane];
  const float4 v1 = ((const float4*)(x + (size_t)(row0 + 1) * D_COLS))[lane];

  // Row maxima (two independent butterflies, interleaved for ILP).
  float m0 = fmaxf(fmaxf(v0.x, v0.y), fmaxf(v0.z, v0.w));
  float m1 = fmaxf(fmaxf(v1.x, v1.y), fmaxf(v1.z, v1.w));
  #pragma unroll
  for (int off = 32; off > 0; off >>= 1) {
    m0 = fmaxf(m0, __shfl_xor(m0, off, 64));
    m1 = fmaxf(m1, __shfl_xor(m1, off, 64));
  }

  float tau0 = m0 - 1.0f, tau1 = m1 - 1.0f;
  int p0 = -1, p1 = -1;

  for (int it = 0; it < 64; ++it) {
    int c0 = __popcll(__ballot(v0.x > tau0)) + __popcll(__ballot(v0.y > tau0)) +
             __popcll(__ballot(v0.z > tau0)) + __popcll(__ballot(v0.w > tau0));
    int c1 = __popcll(__ballot(v1.x > tau1)) + __popcll(__ballot(v1.y > tau1)) +
             __popcll(__ballot(v1.z > tau1)) + __popcll(__ballot(v1.w > tau1));

    if (c0 == p0 && c1 == p1) break;  // both active sets stable => done

    float s0 = ((v0.x > tau0) ? v0.x : 0.0f) + ((v0.y > tau0) ? v0.y : 0.0f) +
               ((v0.z > tau0) ? v0.z : 0.0f) + ((v0.w > tau0) ? v0.w : 0.0f);
    float s1 = ((v1.x > tau1) ? v1.x : 0.0f) + ((v1.y > tau1) ? v1.y : 0.0f) +
               ((v1.z > tau1) ? v1.z : 0.0f) + ((v1.w > tau1) ? v1.w : 0.0f);
    #pragma unroll
    for (int off = 32; off > 0; off >>= 1) {
      s0 += __shfl_xor(s0, off, 64);
      s1 += __shfl_xor(s1, off, 64);
    }

    // Idempotent for an already-stable row: same set => same tau.
    tau0 = (s0 - 1.0f) * FAST_RCP((float)c0);
    tau1 = (s1 - 1.0f) * FAST_RCP((float)c1);
    p0 = c0;
    p1 = c1;
  }

  float4 o0, o1;
  o0.x = fmaxf(v0.x - tau0, 0.0f); o0.y = fmaxf(v0.y - tau0, 0.0f);
  o0.z = fmaxf(v0.z - tau0, 0.0f); o0.w = fmaxf(v0.w - tau0, 0.0f);
  o1.x = fmaxf(v1.x - tau1, 0.0f); o1.y = fmaxf(v1.y - tau1, 0.0f);
  o1.z = fmaxf(v1.z - tau1, 0.0f); o1.w = fmaxf(v1.w - tau1, 0.0f);
  ((float4*)(out + (size_t)row0 * D_COLS))[lane] = o0;
  ((float4*)(out + (size_t)(row0 + 1) * D_COLS))[lane] = o1;
}

extern "C" void kernel_launch(void* const* d_in, const int* in_sizes, int n_in,
                              void* d_out, int out_size, void* d_ws, size_t ws_size,
                              hipStream_t stream) {
  const float* x = (const float*)d_in[0];
  float* out = (float*)d_out;
  const int nrows = in_sizes[0] / D_COLS;
  const int blocks = (nrows + 7) / 8;  // 4 waves/block x 2 rows/wave
  sparsemax_kernel<<<blocks, 256, 0, stream>>>(x, out, nrows);
}

// Round 4
// 226.462 us; speedup vs baseline: 1.0001x; 1.0001x over previous
//
#include <hip/hip_runtime.h>

// Sparsemax over rows: B=131072, D=256, fp32. 2 rows per 64-lane wave.
// All cross-lane reductions via DPP on the VALU pipe (row_shr + row_bcast,
// result in lane 63, v_readlane broadcast) -- NO ds_swizzle: R3 showed the
// kernel is DS-latency-bound (~48 serial DS ops x ~120cyc ~= measured 79us).
// tau via Michelot from A0={z > max-1} (tau* in [max-1, max) => superset).
// rcp_f32 instead of IEEE divide (c is a small int; 1-ulp is plenty).

#define D_COLS 256

#if defined(__has_builtin) && __has_builtin(__builtin_amdgcn_rcpf)
#define FAST_RCP(x) __builtin_amdgcn_rcpf(x)
#else
#define FAST_RCP(x) (1.0f / (x))
#endif

// DPP move with 0-identity: invalid-source lanes contribute 0 under either
// bound_ctrl interpretation (old=0 AND zero-fill both give 0).
#define DPP_MOV0(v, ctrl) \
  __int_as_float(__builtin_amdgcn_update_dpp(0, __float_as_int(v), (ctrl), 0xF, 0xF, true))

// Full-wave sum; valid in lane 63 only. ctrl: row_shr:1/2/4/8, bcast15, bcast31.
__device__ __forceinline__ float wave_sum_l63(float v) {
  v += DPP_MOV0(v, 0x111);
  v += DPP_MOV0(v, 0x112);
  v += DPP_MOV0(v, 0x114);
  v += DPP_MOV0(v, 0x118);
  v += DPP_MOV0(v, 0x142);
  v += DPP_MOV0(v, 0x143);
  return v;
}

// Full-wave max of POSITIVE values (identity 0 safe); valid in lane 63 only.
__device__ __forceinline__ float wave_maxpos_l63(float v) {
  v = fmaxf(v, DPP_MOV0(v, 0x111));
  v = fmaxf(v, DPP_MOV0(v, 0x112));
  v = fmaxf(v, DPP_MOV0(v, 0x114));
  v = fmaxf(v, DPP_MOV0(v, 0x118));
  v = fmaxf(v, DPP_MOV0(v, 0x142));
  v = fmaxf(v, DPP_MOV0(v, 0x143));
  return v;
}

__device__ __forceinline__ float rd63(float v) {
  return __int_as_float(__builtin_amdgcn_readlane(__float_as_int(v), 63));
}

__global__ __launch_bounds__(256) void sparsemax_kernel(
    const float* __restrict__ x, float* __restrict__ out, int nrows) {
  const int wave = threadIdx.x >> 6;
  const int lane = threadIdx.x & 63;
  const int row0 = (blockIdx.x * 4 + wave) * 2;
  if (row0 >= nrows) return;

  const float4 v0 = ((const float4*)(x + (size_t)row0 * D_COLS))[lane];
  const float4 v1 = ((const float4*)(x + (size_t)(row0 + 1) * D_COLS))[lane];

  // Biased per-lane max (bias 1024 => positive for any sane Gaussian input;
  // makes the 0-identity DPP max chain valid). Un-bias is Sterbenz-exact;
  // only the initial +1024 rounds (<=2^-13), far under the 2e-2 threshold.
  float bm0 = fmaxf(fmaxf(v0.x, v0.y), fmaxf(v0.z, v0.w)) + 1024.0f;
  float bm1 = fmaxf(fmaxf(v1.x, v1.y), fmaxf(v1.z, v1.w)) + 1024.0f;
  bm0 = wave_maxpos_l63(bm0);
  bm1 = wave_maxpos_l63(bm1);
  float tau0 = rd63(bm0) - 1025.0f;  // = max - 1
  float tau1 = rd63(bm1) - 1025.0f;
  int p0 = -1, p1 = -1;

  for (int it = 0; it < 64; ++it) {
    int c0 = __popcll(__ballot(v0.x > tau0)) + __popcll(__ballot(v0.y > tau0)) +
             __popcll(__ballot(v0.z > tau0)) + __popcll(__ballot(v0.w > tau0));
    int c1 = __popcll(__ballot(v1.x > tau1)) + __popcll(__ballot(v1.y > tau1)) +
             __popcll(__ballot(v1.z > tau1)) + __popcll(__ballot(v1.w > tau1));

    if (c0 == p0 && c1 == p1) break;  // both active sets stable => done

    float s0 = ((v0.x > tau0) ? v0.x : 0.0f) + ((v0.y > tau0) ? v0.y : 0.0f) +
               ((v0.z > tau0) ? v0.z : 0.0f) + ((v0.w > tau0) ? v0.w : 0.0f);
    float s1 = ((v1.x > tau1) ? v1.x : 0.0f) + ((v1.y > tau1) ? v1.y : 0.0f) +
               ((v1.z > tau1) ? v1.z : 0.0f) + ((v1.w > tau1) ? v1.w : 0.0f);
    s0 = wave_sum_l63(s0);
    s1 = wave_sum_l63(s1);

    // Idempotent for an already-stable row: same set => same tau.
    tau0 = (rd63(s0) - 1.0f) * FAST_RCP((float)c0);
    tau1 = (rd63(s1) - 1.0f) * FAST_RCP((float)c1);
    p0 = c0;
    p1 = c1;
  }

  float4 o0, o1;
  o0.x = fmaxf(v0.x - tau0, 0.0f); o0.y = fmaxf(v0.y - tau0, 0.0f);
  o0.z = fmaxf(v0.z - tau0, 0.0f); o0.w = fmaxf(v0.w - tau0, 0.0f);
  o1.x = fmaxf(v1.x - tau1, 0.0f); o1.y = fmaxf(v1.y - tau1, 0.0f);
  o1.z = fmaxf(v1.z - tau1, 0.0f); o1.w = fmaxf(v1.w - tau1, 0.0f);
  ((float4*)(out + (size_t)row0 * D_COLS))[lane] = o0;
  ((float4*)(out + (size_t)(row0 + 1) * D_COLS))[lane] = o1;
}

extern "C" void kernel_launch(void* const* d_in, const int* in_sizes, int n_in,
                              void* d_out, int out_size, void* d_ws, size_t ws_size,
                              hipStream_t stream) {
  const float* x = (const float*)d_in[0];
  float* out = (float*)d_out;
  const int nrows = in_sizes[0] / D_COLS;
  const int blocks = (nrows + 7) / 8;  // 4 waves/block x 2 rows/wave
  sparsemax_kernel<<<blocks, 256, 0, stream>>>(x, out, nrows);
}